// Round 1
// baseline (756.407 us; speedup 1.0000x reference)
//
#include <hip/hip_runtime.h>
#include <hip/hip_bf16.h>

#define IN_DIM 128
#define HID 64

// ---------------- proj1: xW = x @ Wl1, xWr = x @ Wr1 (128 -> 64, fused) ----
__global__ __launch_bounds__(256) void proj1_kernel(
    const float* __restrict__ x, const float* __restrict__ Wl,
    const float* __restrict__ Wr, float* __restrict__ xW,
    float* __restrict__ xWr, int N) {
  __shared__ float sWl[IN_DIM * HID];  // 32 KB
  __shared__ float sWr[IN_DIM * HID];  // 32 KB
  for (int i = threadIdx.x; i < IN_DIM * HID; i += blockDim.x) {
    sWl[i] = Wl[i];
    sWr[i] = Wr[i];
  }
  __syncthreads();
  const int lane = threadIdx.x & 63;
  const int wave = (blockIdx.x * blockDim.x + threadIdx.x) >> 6;
  const int nwaves = (gridDim.x * blockDim.x) >> 6;
  for (int n = wave; n < N; n += nwaves) {
    const float xa = x[(size_t)n * IN_DIM + lane];
    const float xb = x[(size_t)n * IN_DIM + 64 + lane];
    float accl = 0.f, accr = 0.f;
#pragma unroll
    for (int k = 0; k < 64; ++k) {
      const float xk = __shfl(xa, k);
      accl += xk * sWl[k * HID + lane];
      accr += xk * sWr[k * HID + lane];
    }
#pragma unroll
    for (int k = 0; k < 64; ++k) {
      const float xk = __shfl(xb, k);
      accl += xk * sWl[(64 + k) * HID + lane];
      accr += xk * sWr[(64 + k) * HID + lane];
    }
    xW[(size_t)n * HID + lane] = accl;
    xWr[(size_t)n * HID + lane] = accr;
  }
}

// ---------------- scatter1: agg1[dst] += xW[src]; deg[dst] += 1 ------------
__global__ __launch_bounds__(256) void scatter1_kernel(
    const int* __restrict__ ei, const float* __restrict__ xW,
    float* __restrict__ agg1, float* __restrict__ deg, int E) {
  const long long total = (long long)E * 64;
  const long long stride = (long long)gridDim.x * blockDim.x;
  for (long long t = (long long)blockIdx.x * blockDim.x + threadIdx.x;
       t < total; t += stride) {
    const int e = (int)(t >> 6);
    const int j = (int)(t & 63);
    const int s = ei[e];
    const int d = ei[E + e];
    atomicAdd(&agg1[(size_t)d * HID + j], xW[(size_t)s * HID + j]);
    if (j == 0) atomicAdd(&deg[d], 1.0f);
  }
}

// ---------------- h = relu(agg1/deg + xWr + b1), in-place into agg1 --------
__global__ __launch_bounds__(256) void h_kernel(
    float* __restrict__ agg1, const float* __restrict__ xWr,
    const float* __restrict__ b1, const float* __restrict__ deg, int N) {
  const int total = N * HID;
  const int stride = gridDim.x * blockDim.x;
  for (int i = blockIdx.x * blockDim.x + threadIdx.x; i < total; i += stride) {
    const int n = i >> 6;
    const float dinv = 1.0f / fmaxf(deg[n], 1.0f);
    const float v = agg1[i] * dinv + xWr[i] + b1[i & 63];
    agg1[i] = fmaxf(v, 0.0f);
  }
}

// ---------------- proj2: pl = h @ Wl2, pr = h @ Wr2 (64 -> 3) --------------
__global__ __launch_bounds__(256) void proj2_kernel(
    const float* __restrict__ h, const float* __restrict__ Wl2,
    const float* __restrict__ Wr2, float* __restrict__ pl,
    float* __restrict__ pr, int N) {
  const int lane = threadIdx.x & 63;
  const float wl0 = Wl2[lane * 3 + 0], wl1 = Wl2[lane * 3 + 1],
              wl2v = Wl2[lane * 3 + 2];
  const float wr0 = Wr2[lane * 3 + 0], wr1 = Wr2[lane * 3 + 1],
              wr2v = Wr2[lane * 3 + 2];
  const int wave = (blockIdx.x * blockDim.x + threadIdx.x) >> 6;
  const int nwaves = (gridDim.x * blockDim.x) >> 6;
  for (int n = wave; n < N; n += nwaves) {
    const float hv = h[(size_t)n * HID + lane];
    float v0 = hv * wl0, v1 = hv * wl1, v2 = hv * wl2v;
    float v3 = hv * wr0, v4 = hv * wr1, v5 = hv * wr2v;
#pragma unroll
    for (int off = 32; off >= 1; off >>= 1) {
      v0 += __shfl_down(v0, off);
      v1 += __shfl_down(v1, off);
      v2 += __shfl_down(v2, off);
      v3 += __shfl_down(v3, off);
      v4 += __shfl_down(v4, off);
      v5 += __shfl_down(v5, off);
    }
    if (lane == 0) {
      pl[(size_t)n * 3 + 0] = v0;
      pl[(size_t)n * 3 + 1] = v1;
      pl[(size_t)n * 3 + 2] = v2;
      pr[(size_t)n * 3 + 0] = v3;
      pr[(size_t)n * 3 + 1] = v4;
      pr[(size_t)n * 3 + 2] = v5;
    }
  }
}

// ---------------- scatter2: agg2[dst] += pl[src] ---------------------------
__global__ __launch_bounds__(256) void scatter2_kernel(
    const int* __restrict__ ei, const float* __restrict__ pl,
    float* __restrict__ agg2, int E) {
  const int stride = gridDim.x * blockDim.x;
  for (int e = blockIdx.x * blockDim.x + threadIdx.x; e < E; e += stride) {
    const int s = ei[e];
    const int d = ei[E + e];
    atomicAdd(&agg2[(size_t)d * 3 + 0], pl[(size_t)s * 3 + 0]);
    atomicAdd(&agg2[(size_t)d * 3 + 1], pl[(size_t)s * 3 + 1]);
    atomicAdd(&agg2[(size_t)d * 3 + 2], pl[(size_t)s * 3 + 2]);
  }
}

// ---------------- final: out = log_softmax(agg2/deg + pr + b2) -------------
__global__ __launch_bounds__(256) void final_kernel(
    const float* __restrict__ agg2, const float* __restrict__ pr,
    const float* __restrict__ b2, const float* __restrict__ deg,
    float* __restrict__ out, int N) {
  const int stride = gridDim.x * blockDim.x;
  const float b20 = b2[0], b21 = b2[1], b22 = b2[2];
  for (int n = blockIdx.x * blockDim.x + threadIdx.x; n < N; n += stride) {
    const float dinv = 1.0f / fmaxf(deg[n], 1.0f);
    const float v0 = agg2[(size_t)n * 3 + 0] * dinv + pr[(size_t)n * 3 + 0] + b20;
    const float v1 = agg2[(size_t)n * 3 + 1] * dinv + pr[(size_t)n * 3 + 1] + b21;
    const float v2 = agg2[(size_t)n * 3 + 2] * dinv + pr[(size_t)n * 3 + 2] + b22;
    const float m = fmaxf(fmaxf(v0, v1), v2);
    const float e0 = __expf(v0 - m), e1 = __expf(v1 - m), e2 = __expf(v2 - m);
    const float lse = __logf(e0 + e1 + e2);
    out[(size_t)n * 3 + 0] = v0 - m - lse;
    out[(size_t)n * 3 + 1] = v1 - m - lse;
    out[(size_t)n * 3 + 2] = v2 - m - lse;
  }
}

extern "C" void kernel_launch(void* const* d_in, const int* in_sizes, int n_in,
                              void* d_out, int out_size, void* d_ws,
                              size_t ws_size, hipStream_t stream) {
  const float* x = (const float*)d_in[0];
  const int* ei = (const int*)d_in[1];  // int64 in ref, but JAX x64 off -> int32
  const float* Wl1 = (const float*)d_in[2];
  const float* Wr1 = (const float*)d_in[3];
  const float* b1 = (const float*)d_in[4];
  const float* Wl2 = (const float*)d_in[5];
  const float* Wr2 = (const float*)d_in[6];
  const float* b2 = (const float*)d_in[7];
  float* out = (float*)d_out;

  const int N = in_sizes[0] / IN_DIM;
  const int E = in_sizes[1] / 2;

  // Workspace layout (floats). Zeroed region first (deg|agg1|agg2 contiguous).
  float* ws = (float*)d_ws;
  float* deg = ws;                          // [N]
  float* agg1 = deg + N;                    // [N*64]
  float* agg2 = agg1 + (size_t)N * HID;     // [N*3]
  float* xW = agg2 + (size_t)N * 3;         // [N*64]
  float* xWr = xW + (size_t)N * HID;        // [N*64]
  float* pl = xWr + (size_t)N * HID;        // [N*3]
  float* pr = pl + (size_t)N * 3;           // [N*3]

  hipMemsetAsync(deg, 0, (size_t)N * (1 + HID + 3) * sizeof(float), stream);

  proj1_kernel<<<512, 256, 0, stream>>>(x, Wl1, Wr1, xW, xWr, N);
  scatter1_kernel<<<2048, 256, 0, stream>>>(ei, xW, agg1, deg, E);
  h_kernel<<<1024, 256, 0, stream>>>(agg1, xWr, b1, deg, N);
  proj2_kernel<<<1024, 256, 0, stream>>>(agg1, Wl2, Wr2, pl, pr, N);
  scatter2_kernel<<<1024, 256, 0, stream>>>(ei, pl, agg2, E);
  final_kernel<<<512, 256, 0, stream>>>(agg2, pr, b2, deg, out, N);
}

// Round 2
// 383.148 us; speedup vs baseline: 1.9742x; 1.9742x over previous
//
#include <hip/hip_runtime.h>
#include <hip/hip_bf16.h>

#define IN_DIM 128
#define HID 64
#define BM 128
#define BN 128
#define BK 32

// ---- proj1: [xW | xWr] = x @ [Wl1 | Wr1]  (N x 128) @ (128 x 128) ---------
// Register-tiled fp32 GEMM: 256 thr, each owns 8 nodes x 8 outputs.
__global__ __launch_bounds__(256) void proj1_kernel(
    const float* __restrict__ x, const float* __restrict__ Wl,
    const float* __restrict__ Wr, float* __restrict__ xW,
    float* __restrict__ xWr, int N) {
  __shared__ float xs[BK][BM];  // x tile, transposed: 16 KB
  __shared__ float ws[BK][BN];  // [Wl|Wr] tile: 16 KB
  const int tx = threadIdx.x;
  const int c = tx & 15;   // output group: outs c*8 .. c*8+7
  const int r = tx >> 4;   // node group:   nodes r*8 .. r*8+7
  const int n0 = blockIdx.x * BM;

  float acc[8][8];
#pragma unroll
  for (int i = 0; i < 8; ++i)
#pragma unroll
    for (int j = 0; j < 8; ++j) acc[i][j] = 0.f;

  // staging maps
  const int ln = tx >> 1;            // node 0..127 within tile
  const int lk = (tx & 1) * 16;      // k half: 0 or 16
  const int gnode = n0 + ln;
  const int wk = tx >> 3;            // W row 0..31 within chunk
  const int wc = (tx & 7) * 16;      // W col start 0..112

  for (int k0 = 0; k0 < IN_DIM; k0 += BK) {
    if (gnode < N) {
      const float4* xp =
          (const float4*)&x[(size_t)gnode * IN_DIM + k0 + lk];
#pragma unroll
      for (int q = 0; q < 4; ++q) {
        const float4 v = xp[q];
        xs[lk + q * 4 + 0][ln] = v.x;
        xs[lk + q * 4 + 1][ln] = v.y;
        xs[lk + q * 4 + 2][ln] = v.z;
        xs[lk + q * 4 + 3][ln] = v.w;
      }
    } else {
#pragma unroll
      for (int q = 0; q < 16; ++q) xs[lk + q][ln] = 0.f;
    }
#pragma unroll
    for (int q = 0; q < 4; ++q) {
      const int col = wc + q * 4;  // multiple of 4, never straddles 64
      const float4 v = (col < 64)
          ? *(const float4*)&Wl[(size_t)(k0 + wk) * HID + col]
          : *(const float4*)&Wr[(size_t)(k0 + wk) * HID + (col - 64)];
      *(float4*)&ws[wk][col] = v;
    }
    __syncthreads();
#pragma unroll
    for (int k = 0; k < BK; ++k) {
      float a[8], b[8];
      *(float4*)&a[0] = *(const float4*)&xs[k][r * 8];
      *(float4*)&a[4] = *(const float4*)&xs[k][r * 8 + 4];
      *(float4*)&b[0] = *(const float4*)&ws[k][c * 8];
      *(float4*)&b[4] = *(const float4*)&ws[k][c * 8 + 4];
#pragma unroll
      for (int i = 0; i < 8; ++i)
#pragma unroll
        for (int j = 0; j < 8; ++j) acc[i][j] += a[i] * b[j];
    }
    __syncthreads();
  }
#pragma unroll
  for (int i = 0; i < 8; ++i) {
    const int n = n0 + r * 8 + i;
    if (n < N) {
      float* dst = (c < 8) ? &xW[(size_t)n * HID + c * 8]
                           : &xWr[(size_t)n * HID + (c - 8) * 8];
      *(float4*)&dst[0] = *(float4*)&acc[i][0];
      *(float4*)&dst[4] = *(float4*)&acc[i][4];
    }
  }
}

// ---- scatter1: agg1[dst] += xW[src]; deg[dst] += 1  (wave per edge) -------
__global__ __launch_bounds__(256) void scatter1_kernel(
    const int* __restrict__ ei, const float* __restrict__ xW,
    float* __restrict__ agg1, float* __restrict__ deg, int E) {
  const long long total = (long long)E * 64;
  const long long stride = (long long)gridDim.x * blockDim.x;
  for (long long t = (long long)blockIdx.x * blockDim.x + threadIdx.x;
       t < total; t += stride) {
    const int e = (int)(t >> 6);
    const int j = (int)(t & 63);
    const int s = ei[e];
    const int d = ei[E + e];
    atomicAdd(&agg1[(size_t)d * HID + j], xW[(size_t)s * HID + j]);
    if (j == 0) atomicAdd(&deg[d], 1.0f);
  }
}

// ---- proj2 (fused h): hv = relu(agg1/deg + xWr + b1); pl=h@Wl2, pr=h@Wr2 --
__global__ __launch_bounds__(256) void proj2_kernel(
    const float* __restrict__ agg1, const float* __restrict__ xWr1,
    const float* __restrict__ b1, const float* __restrict__ deg,
    const float* __restrict__ Wl2, const float* __restrict__ Wr2,
    float* __restrict__ pl, float* __restrict__ pr, int N) {
  const int lane = threadIdx.x & 63;
  const float wl0 = Wl2[lane * 3 + 0], wl1 = Wl2[lane * 3 + 1],
              wl2v = Wl2[lane * 3 + 2];
  const float wr0 = Wr2[lane * 3 + 0], wr1 = Wr2[lane * 3 + 1],
              wr2v = Wr2[lane * 3 + 2];
  const float bb = b1[lane];
  const int wave = (blockIdx.x * blockDim.x + threadIdx.x) >> 6;
  const int nwaves = (gridDim.x * blockDim.x) >> 6;
  for (int n = wave; n < N; n += nwaves) {
    const float dinv = 1.0f / fmaxf(deg[n], 1.0f);
    const float hv = fmaxf(
        agg1[(size_t)n * HID + lane] * dinv + xWr1[(size_t)n * HID + lane] + bb,
        0.0f);
    float v0 = hv * wl0, v1 = hv * wl1, v2 = hv * wl2v;
    float v3 = hv * wr0, v4 = hv * wr1, v5 = hv * wr2v;
#pragma unroll
    for (int off = 32; off >= 1; off >>= 1) {
      v0 += __shfl_down(v0, off);
      v1 += __shfl_down(v1, off);
      v2 += __shfl_down(v2, off);
      v3 += __shfl_down(v3, off);
      v4 += __shfl_down(v4, off);
      v5 += __shfl_down(v5, off);
    }
    if (lane == 0) {
      pl[(size_t)n * 3 + 0] = v0;
      pl[(size_t)n * 3 + 1] = v1;
      pl[(size_t)n * 3 + 2] = v2;
      pr[(size_t)n * 3 + 0] = v3;
      pr[(size_t)n * 3 + 1] = v4;
      pr[(size_t)n * 3 + 2] = v5;
    }
  }
}

// ---- scatter2: agg2[dst] += pl[src] ---------------------------------------
__global__ __launch_bounds__(256) void scatter2_kernel(
    const int* __restrict__ ei, const float* __restrict__ pl,
    float* __restrict__ agg2, int E) {
  const int stride = gridDim.x * blockDim.x;
  for (int e = blockIdx.x * blockDim.x + threadIdx.x; e < E; e += stride) {
    const int s = ei[e];
    const int d = ei[E + e];
    atomicAdd(&agg2[(size_t)d * 3 + 0], pl[(size_t)s * 3 + 0]);
    atomicAdd(&agg2[(size_t)d * 3 + 1], pl[(size_t)s * 3 + 1]);
    atomicAdd(&agg2[(size_t)d * 3 + 2], pl[(size_t)s * 3 + 2]);
  }
}

// ---- final: out = log_softmax(agg2/deg + pr + b2) -------------------------
__global__ __launch_bounds__(256) void final_kernel(
    const float* __restrict__ agg2, const float* __restrict__ pr,
    const float* __restrict__ b2, const float* __restrict__ deg,
    float* __restrict__ out, int N) {
  const int stride = gridDim.x * blockDim.x;
  const float b20 = b2[0], b21 = b2[1], b22 = b2[2];
  for (int n = blockIdx.x * blockDim.x + threadIdx.x; n < N; n += stride) {
    const float dinv = 1.0f / fmaxf(deg[n], 1.0f);
    const float v0 = agg2[(size_t)n * 3 + 0] * dinv + pr[(size_t)n * 3 + 0] + b20;
    const float v1 = agg2[(size_t)n * 3 + 1] * dinv + pr[(size_t)n * 3 + 1] + b21;
    const float v2 = agg2[(size_t)n * 3 + 2] * dinv + pr[(size_t)n * 3 + 2] + b22;
    const float m = fmaxf(fmaxf(v0, v1), v2);
    const float e0 = __expf(v0 - m), e1 = __expf(v1 - m), e2 = __expf(v2 - m);
    const float lse = __logf(e0 + e1 + e2);
    out[(size_t)n * 3 + 0] = v0 - m - lse;
    out[(size_t)n * 3 + 1] = v1 - m - lse;
    out[(size_t)n * 3 + 2] = v2 - m - lse;
  }
}

extern "C" void kernel_launch(void* const* d_in, const int* in_sizes, int n_in,
                              void* d_out, int out_size, void* d_ws,
                              size_t ws_size, hipStream_t stream) {
  const float* x = (const float*)d_in[0];
  const int* ei = (const int*)d_in[1];  // int32 (JAX x64 disabled)
  const float* Wl1 = (const float*)d_in[2];
  const float* Wr1 = (const float*)d_in[3];
  const float* b1 = (const float*)d_in[4];
  const float* Wl2 = (const float*)d_in[5];
  const float* Wr2 = (const float*)d_in[6];
  const float* b2 = (const float*)d_in[7];
  float* out = (float*)d_out;

  const int N = in_sizes[0] / IN_DIM;
  const int E = in_sizes[1] / 2;

  float* ws = (float*)d_ws;
  float* deg = ws;                       // [N]
  float* agg1 = deg + N;                 // [N*64]  raw sums
  float* agg2 = agg1 + (size_t)N * HID;  // [N*3]   raw sums
  float* xW = agg2 + (size_t)N * 3;      // [N*64]
  float* xWr = xW + (size_t)N * HID;     // [N*64]
  float* pl = xWr + (size_t)N * HID;     // [N*3]
  float* pr = pl + (size_t)N * 3;        // [N*3]

  hipMemsetAsync(deg, 0, (size_t)N * (1 + HID + 3) * sizeof(float), stream);

  proj1_kernel<<<(N + BM - 1) / BM, 256, 0, stream>>>(x, Wl1, Wr1, xW, xWr, N);
  scatter1_kernel<<<2048, 256, 0, stream>>>(ei, xW, agg1, deg, E);
  proj2_kernel<<<1024, 256, 0, stream>>>(agg1, xWr, b1, deg, Wl2, Wr2, pl, pr,
                                         N);
  scatter2_kernel<<<1024, 256, 0, stream>>>(ei, pl, agg2, E);
  final_kernel<<<512, 256, 0, stream>>>(agg2, pr, b2, deg, out, N);
}

// Round 3
// 217.201 us; speedup vs baseline: 3.4825x; 1.7640x over previous
//
#include <hip/hip_runtime.h>
#include <hip/hip_bf16.h>

#define IN_DIM 128
#define HID 64
#define BM 128
#define BN 128
#define BK 32
#define SCAN_B 1024

// ---- proj1: [xW | xWr] = x @ [Wl1 | Wr1]  (N x 128) @ (128 x 128) ---------
__global__ __launch_bounds__(256) void proj1_kernel(
    const float* __restrict__ x, const float* __restrict__ Wl,
    const float* __restrict__ Wr, float* __restrict__ xW,
    float* __restrict__ xWr, int N) {
  __shared__ float xs[BK][BM];
  __shared__ float ws[BK][BN];
  const int tx = threadIdx.x;
  const int c = tx & 15;
  const int r = tx >> 4;
  const int n0 = blockIdx.x * BM;

  float acc[8][8];
#pragma unroll
  for (int i = 0; i < 8; ++i)
#pragma unroll
    for (int j = 0; j < 8; ++j) acc[i][j] = 0.f;

  const int ln = tx >> 1;
  const int lk = (tx & 1) * 16;
  const int gnode = n0 + ln;
  const int wk = tx >> 3;
  const int wc = (tx & 7) * 16;

  for (int k0 = 0; k0 < IN_DIM; k0 += BK) {
    if (gnode < N) {
      const float4* xp = (const float4*)&x[(size_t)gnode * IN_DIM + k0 + lk];
#pragma unroll
      for (int q = 0; q < 4; ++q) {
        const float4 v = xp[q];
        xs[lk + q * 4 + 0][ln] = v.x;
        xs[lk + q * 4 + 1][ln] = v.y;
        xs[lk + q * 4 + 2][ln] = v.z;
        xs[lk + q * 4 + 3][ln] = v.w;
      }
    } else {
#pragma unroll
      for (int q = 0; q < 16; ++q) xs[lk + q][ln] = 0.f;
    }
#pragma unroll
    for (int q = 0; q < 4; ++q) {
      const int col = wc + q * 4;
      const float4 v = (col < 64)
          ? *(const float4*)&Wl[(size_t)(k0 + wk) * HID + col]
          : *(const float4*)&Wr[(size_t)(k0 + wk) * HID + (col - 64)];
      *(float4*)&ws[wk][col] = v;
    }
    __syncthreads();
#pragma unroll
    for (int k = 0; k < BK; ++k) {
      float a[8], b[8];
      *(float4*)&a[0] = *(const float4*)&xs[k][r * 8];
      *(float4*)&a[4] = *(const float4*)&xs[k][r * 8 + 4];
      *(float4*)&b[0] = *(const float4*)&ws[k][c * 8];
      *(float4*)&b[4] = *(const float4*)&ws[k][c * 8 + 4];
#pragma unroll
      for (int i = 0; i < 8; ++i)
#pragma unroll
        for (int j = 0; j < 8; ++j) acc[i][j] += a[i] * b[j];
    }
    __syncthreads();
  }
#pragma unroll
  for (int i = 0; i < 8; ++i) {
    const int n = n0 + r * 8 + i;
    if (n < N) {
      float* dst = (c < 8) ? &xW[(size_t)n * HID + c * 8]
                           : &xWr[(size_t)n * HID + (c - 8) * 8];
      *(float4*)&dst[0] = *(float4*)&acc[i][0];
      *(float4*)&dst[4] = *(float4*)&acc[i][4];
    }
  }
}

// ---- CSR build ------------------------------------------------------------
__global__ __launch_bounds__(256) void count_kernel(const int* __restrict__ ei,
                                                    int* __restrict__ deg_i,
                                                    int E) {
  const int e = blockIdx.x * blockDim.x + threadIdx.x;
  if (e < E) atomicAdd(&deg_i[ei[E + e]], 1);
}

__global__ __launch_bounds__(SCAN_B) void scan1_kernel(
    const int* __restrict__ in, int* __restrict__ incl, int* __restrict__ bsum,
    int n) {
  __shared__ int s[SCAN_B];
  const int t = threadIdx.x;
  const int i = blockIdx.x * SCAN_B + t;
  int v = (i < n) ? in[i] : 0;
  s[t] = v;
  for (int off = 1; off < SCAN_B; off <<= 1) {
    __syncthreads();
    const int a = (t >= off) ? s[t - off] : 0;
    __syncthreads();
    s[t] += a;
  }
  if (i < n) incl[i] = s[t];
  if (t == SCAN_B - 1) bsum[blockIdx.x] = s[t];
}

__global__ __launch_bounds__(SCAN_B) void scan2_kernel(
    const int* __restrict__ bsum, int* __restrict__ boff, int nb) {
  __shared__ int s[SCAN_B];
  const int t = threadIdx.x;
  const int v = (t < nb) ? bsum[t] : 0;
  s[t] = v;
  for (int off = 1; off < SCAN_B; off <<= 1) {
    __syncthreads();
    const int a = (t >= off) ? s[t - off] : 0;
    __syncthreads();
    s[t] += a;
  }
  if (t < nb) boff[t] = s[t] - v;  // exclusive
}

__global__ __launch_bounds__(256) void scan3_kernel(
    const int* __restrict__ incl, const int* __restrict__ deg_i,
    const int* __restrict__ boff, int* __restrict__ row_off,
    int* __restrict__ cursor, int n) {
  const int i = blockIdx.x * blockDim.x + threadIdx.x;
  if (i < n) {
    const int st = incl[i] - deg_i[i] + boff[i >> 10];
    row_off[i] = st;
    cursor[i] = st;
  }
}

__global__ __launch_bounds__(256) void fill_kernel(const int* __restrict__ ei,
                                                   int* __restrict__ cursor,
                                                   int* __restrict__ csr_src,
                                                   int E) {
  const int e = blockIdx.x * blockDim.x + threadIdx.x;
  if (e < E) {
    const int s = ei[e];
    const int d = ei[E + e];
    const int pos = atomicAdd(&cursor[d], 1);
    csr_src[pos] = s;
  }
}

// ---- gather1: agg = sum_j xW[src]; h = relu(agg/deg + xWr + b1);
//      pl = h @ Wl2, pr = h @ Wr2  (all fused, wave per node) ---------------
__global__ __launch_bounds__(256) void gather1_kernel(
    const int* __restrict__ row_off, const int* __restrict__ deg_i,
    const int* __restrict__ csr_src, const float* __restrict__ xW,
    const float* __restrict__ xWr, const float* __restrict__ b1,
    const float* __restrict__ Wl2, const float* __restrict__ Wr2,
    float* __restrict__ pl, float* __restrict__ pr, int N) {
  const int lane = threadIdx.x & 63;
  const float wl0 = Wl2[lane * 3 + 0], wl1 = Wl2[lane * 3 + 1],
              wl2v = Wl2[lane * 3 + 2];
  const float wr0 = Wr2[lane * 3 + 0], wr1 = Wr2[lane * 3 + 1],
              wr2v = Wr2[lane * 3 + 2];
  const float bb = b1[lane];
  const int wave = (blockIdx.x * blockDim.x + threadIdx.x) >> 6;
  const int nwaves = (gridDim.x * blockDim.x) >> 6;
  for (int n = wave; n < N; n += nwaves) {
    const int start = row_off[n];
    const int dg = deg_i[n];
    float a0 = 0.f, a1 = 0.f;
    int r = 0;
    for (; r + 1 < dg; r += 2) {
      const int s0 = csr_src[start + r];
      const int s1 = csr_src[start + r + 1];
      a0 += xW[(size_t)s0 * HID + lane];
      a1 += xW[(size_t)s1 * HID + lane];
    }
    if (r < dg) a0 += xW[(size_t)csr_src[start + r] * HID + lane];
    const float dinv = 1.0f / fmaxf((float)dg, 1.0f);
    const float hv =
        fmaxf((a0 + a1) * dinv + xWr[(size_t)n * HID + lane] + bb, 0.0f);
    float v0 = hv * wl0, v1 = hv * wl1, v2 = hv * wl2v;
    float v3 = hv * wr0, v4 = hv * wr1, v5 = hv * wr2v;
#pragma unroll
    for (int off = 32; off >= 1; off >>= 1) {
      v0 += __shfl_down(v0, off);
      v1 += __shfl_down(v1, off);
      v2 += __shfl_down(v2, off);
      v3 += __shfl_down(v3, off);
      v4 += __shfl_down(v4, off);
      v5 += __shfl_down(v5, off);
    }
    if (lane == 0) {
      pl[(size_t)n * 3 + 0] = v0;
      pl[(size_t)n * 3 + 1] = v1;
      pl[(size_t)n * 3 + 2] = v2;
      pr[(size_t)n * 3 + 0] = v3;
      pr[(size_t)n * 3 + 1] = v4;
      pr[(size_t)n * 3 + 2] = v5;
    }
  }
}

// ---- final: gather pl over neighbors, log_softmax -------------------------
__global__ __launch_bounds__(256) void final_kernel(
    const int* __restrict__ row_off, const int* __restrict__ deg_i,
    const int* __restrict__ csr_src, const float* __restrict__ pl,
    const float* __restrict__ pr, const float* __restrict__ b2,
    float* __restrict__ out, int N) {
  const int stride = gridDim.x * blockDim.x;
  const float b20 = b2[0], b21 = b2[1], b22 = b2[2];
  for (int n = blockIdx.x * blockDim.x + threadIdx.x; n < N; n += stride) {
    const int start = row_off[n];
    const int dg = deg_i[n];
    float s0 = 0.f, s1 = 0.f, s2 = 0.f;
    for (int r = 0; r < dg; ++r) {
      const int s = csr_src[start + r];
      s0 += pl[(size_t)s * 3 + 0];
      s1 += pl[(size_t)s * 3 + 1];
      s2 += pl[(size_t)s * 3 + 2];
    }
    const float dinv = 1.0f / fmaxf((float)dg, 1.0f);
    const float v0 = s0 * dinv + pr[(size_t)n * 3 + 0] + b20;
    const float v1 = s1 * dinv + pr[(size_t)n * 3 + 1] + b21;
    const float v2 = s2 * dinv + pr[(size_t)n * 3 + 2] + b22;
    const float m = fmaxf(fmaxf(v0, v1), v2);
    const float e0 = __expf(v0 - m), e1 = __expf(v1 - m), e2 = __expf(v2 - m);
    const float lse = __logf(e0 + e1 + e2);
    out[(size_t)n * 3 + 0] = v0 - m - lse;
    out[(size_t)n * 3 + 1] = v1 - m - lse;
    out[(size_t)n * 3 + 2] = v2 - m - lse;
  }
}

extern "C" void kernel_launch(void* const* d_in, const int* in_sizes, int n_in,
                              void* d_out, int out_size, void* d_ws,
                              size_t ws_size, hipStream_t stream) {
  const float* x = (const float*)d_in[0];
  const int* ei = (const int*)d_in[1];  // int32 (JAX x64 disabled)
  const float* Wl1 = (const float*)d_in[2];
  const float* Wr1 = (const float*)d_in[3];
  const float* b1 = (const float*)d_in[4];
  const float* Wl2 = (const float*)d_in[5];
  const float* Wr2 = (const float*)d_in[6];
  const float* b2 = (const float*)d_in[7];
  float* out = (float*)d_out;

  const int N = in_sizes[0] / IN_DIM;
  const int E = in_sizes[1] / 2;
  const int nb1 = (N + SCAN_B - 1) / SCAN_B;  // 98 for N=100k (<=1024)

  // Workspace layout (4-byte elements)
  int* wsI = (int*)d_ws;
  int* deg_i = wsI;                 // [N]
  int* row_off = deg_i + N;         // [N]
  int* cursor = row_off + N;        // [N]
  int* incl = cursor + N;           // [N]
  int* bsum = incl + N;             // [SCAN_B]
  int* boff = bsum + SCAN_B;        // [SCAN_B]
  int* csr_src = boff + SCAN_B;     // [E]
  float* xW = (float*)(csr_src + E);        // [N*64]
  float* xWr = xW + (size_t)N * HID;        // [N*64]
  float* pl = xWr + (size_t)N * HID;        // [N*3]
  float* pr = pl + (size_t)N * 3;           // [N*3]

  hipMemsetAsync(deg_i, 0, (size_t)N * sizeof(int), stream);

  proj1_kernel<<<(N + BM - 1) / BM, 256, 0, stream>>>(x, Wl1, Wr1, xW, xWr, N);
  count_kernel<<<(E + 255) / 256, 256, 0, stream>>>(ei, deg_i, E);
  scan1_kernel<<<nb1, SCAN_B, 0, stream>>>(deg_i, incl, bsum, N);
  scan2_kernel<<<1, SCAN_B, 0, stream>>>(bsum, boff, nb1);
  scan3_kernel<<<(N + 255) / 256, 256, 0, stream>>>(incl, deg_i, boff, row_off,
                                                    cursor, N);
  fill_kernel<<<(E + 255) / 256, 256, 0, stream>>>(ei, cursor, csr_src, E);
  gather1_kernel<<<2048, 256, 0, stream>>>(row_off, deg_i, csr_src, xW, xWr,
                                           b1, Wl2, Wr2, pl, pr, N);
  final_kernel<<<(N + 255) / 256, 256, 0, stream>>>(row_off, deg_i, csr_src,
                                                    pl, pr, b2, out, N);
}